// Round 10
// baseline (4722.596 us; speedup 1.0000x reference)
//
#include <hip/hip_runtime.h>
#include <cstdint>
#include <cstddef>

#define B_ 512
#define T_ 2048
#define D_ 64
#define H_ 48
#define C_ 3
#define LCH 16           // chunk length
#define KCH 128          // chunks per batch
#define NC  65536        // total chains = B_*KCH

#define RECON_FLOATS ((size_t)B_ * T_ * D_)            // 67,108,864 floats (output 0)
#define LOGIT_FLOATS ((size_t)B_ * C_)                 // 1536 floats      (output 1)
#define Z_OFF        (RECON_FLOATS + LOGIT_FLOATS)     // z region         (output 2)
// scratch inside the recon region (dec overwrites it LAST):
// u (std layout [b][t][48]) at 0 .. 50,331,648
#define S0_OFF   ((size_t)50331648)                    // S0[c][48]
#define MIN_OFF  ((size_t)53477376)                    // M_in[c][48]
#define ZP_OFF   ((size_t)56623104)                    // zsum_part[c][48]
#define A16_OFF  ((size_t)59768832)                    // A^16 (2304 floats)

// ---------------- encoder GEMM (round-8 verbatim): u[r][48] = x row . Wenc^T + (benc+bmem) ----------------
__global__ __launch_bounds__(128) void k_enc(
    const float* __restrict__ x, const float* __restrict__ Wenc,
    const float* __restrict__ benc, const float* __restrict__ bmem,
    float* __restrict__ out)
{
    __shared__ float sx[128][68];
    __shared__ float sw[48][68];
    __shared__ float sbe[48];

    const int tid = threadIdx.x;

    {
        const float4* wf4 = reinterpret_cast<const float4*>(Wenc);
        #pragma unroll
        for (int m = 0; m < 6; ++m) {
            const int idx = tid + 128 * m;
            const int c = idx >> 4, d4 = idx & 15;
            *reinterpret_cast<float4*>(&sw[c][d4 * 4]) = wf4[idx];
        }
    }
    if (tid < 48) sbe[tid] = benc[tid] + bmem[tid];

    {
        const float4* xf4 = reinterpret_cast<const float4*>(x) + (size_t)blockIdx.x * 2048;
        #pragma unroll
        for (int m = 0; m < 16; ++m) {
            const int idx = tid + 128 * m;
            const int row = idx >> 4, d4 = idx & 15;
            *reinterpret_cast<float4*>(&sx[row][d4 * 4]) = xf4[idx];
        }
    }
    __syncthreads();

    const int lane = tid & 63;
    const int wv   = tid >> 6;
    const int rg   = lane >> 2;
    const int cg   = lane & 3;
    const int rowb = wv * 64 + rg;
    const int colb = cg * 12;

    float acc[4][12];
    {
        float bia[12];
        #pragma unroll
        for (int m = 0; m < 3; ++m)
            *reinterpret_cast<float4*>(&bia[4 * m]) = *reinterpret_cast<const float4*>(&sbe[colb + 4 * m]);
        #pragma unroll
        for (int k = 0; k < 4; ++k)
            #pragma unroll
            for (int i = 0; i < 12; ++i) acc[k][i] = bia[i];
    }

    #pragma unroll 2
    for (int d4 = 0; d4 < 16; ++d4) {
        float4 xf[4];
        #pragma unroll
        for (int k = 0; k < 4; ++k)
            xf[k] = *reinterpret_cast<const float4*>(&sx[rowb + 16 * k][d4 * 4]);
        #pragma unroll
        for (int i = 0; i < 12; ++i) {
            const float4 wvv = *reinterpret_cast<const float4*>(&sw[colb + i][d4 * 4]);
            #pragma unroll
            for (int k = 0; k < 4; ++k)
                acc[k][i] = fmaf(xf[k].x, wvv.x, fmaf(xf[k].y, wvv.y,
                             fmaf(xf[k].z, wvv.z, fmaf(xf[k].w, wvv.w, acc[k][i]))));
        }
    }

    const size_t row0 = (size_t)blockIdx.x * 128 + rowb;
    #pragma unroll
    for (int k = 0; k < 4; ++k) {
        float* dst = out + (row0 + 16 * k) * 48 + colb;
        #pragma unroll
        for (int m = 0; m < 3; ++m)
            *reinterpret_cast<float4*>(dst + 4 * m) =
                make_float4(acc[k][4 * m], acc[k][4 * m + 1], acc[k][4 * m + 2], acc[k][4 * m + 3]);
    }
}

// ---------------- A^16 via 4 squarings ----------------
__global__ __launch_bounds__(576) void k_powA(
    const float* __restrict__ Wmem, float* __restrict__ out)
{
    __shared__ float a0[48 * 49];
    __shared__ float a1[48 * 49];
    const int tid = threadIdx.x;

    for (int idx = tid; idx < 2304; idx += 576) {
        const int i = idx / 48, j = idx - i * 48;
        a0[i * 49 + j] = 0.1f * Wmem[idx] + (i == j ? 0.9f : 0.0f);
    }
    __syncthreads();

    float* src = a0;
    float* dst = a1;
    #pragma unroll 1
    for (int it = 0; it < 4; ++it) {
        float v[4];
        #pragma unroll
        for (int q = 0; q < 4; ++q) {
            const int o = tid + 576 * q;
            const int i = o / 48, j = o - i * 48;
            float acc = 0.f;
            #pragma unroll
            for (int k = 0; k < 48; ++k)
                acc = fmaf(src[i * 49 + k], src[k * 49 + j], acc);
            v[q] = acc;
        }
        #pragma unroll
        for (int q = 0; q < 4; ++q) {
            const int o = tid + 576 * q;
            const int i = o / 48, j = o - i * 48;
            dst[i * 49 + j] = v[q];
        }
        __syncthreads();
        float* t = src; src = dst; dst = t;
    }
    for (int idx = tid; idx < 2304; idx += 576) {
        const int i = idx / 48, j = idx - i * 48;
        out[A16_OFF + idx] = src[i * 49 + j];
    }
}

// fma of float4 a (A col chunk) * scalar m into float4 acc
#define FMA4(accq, a, mval) \
    accq.x = fmaf((a).x, (mval), accq.x); \
    accq.y = fmaf((a).y, (mval), accq.y); \
    accq.z = fmaf((a).z, (mval), accq.z); \
    accq.w = fmaf((a).w, (mval), accq.w);

// acc += A * mo   (sAT col-major in LDS; float4-native, static indexing only)
#define AMV_COL(e, mval)                                                        \
    {                                                                           \
        const float* colp = sAT + (4 * j4 + (e)) * 48;                          \
        _Pragma("unroll")                                                       \
        for (int q = 0; q < 12; ++q) {                                          \
            const float4 a = *reinterpret_cast<const float4*>(colp + 4 * q);    \
            FMA4(acc[q], a, (mval));                                            \
        }                                                                       \
    }

// ---------------- phase 1: zero-init chunk-end states; chain-per-lane, float4 state ----------------
__global__ __launch_bounds__(256) void k_p1(
    const float* __restrict__ Wmem, float* __restrict__ out)
{
    __shared__ float sAT[48 * 48];
    const int tid = threadIdx.x;
    for (int idx = tid; idx < 2304; idx += 256) {
        const int i = idx / 48, j = idx - i * 48;
        sAT[j * 48 + i] = 0.1f * Wmem[idx] + (i == j ? 0.9f : 0.0f);
    }
    __syncthreads();

    const size_t c = (size_t)blockIdx.x * 256 + tid;
    const float4* ub4 = reinterpret_cast<const float4*>(out + c * 768);  // chain's u block, 12 f4/step

    float4 mo[12], ubuf[12];
    #pragma unroll
    for (int q = 0; q < 12; ++q) mo[q] = make_float4(0.f, 0.f, 0.f, 0.f);
    #pragma unroll
    for (int q = 0; q < 12; ++q) ubuf[q] = ub4[q];

    #pragma unroll 1
    for (int s = 0; s < LCH; ++s) {
        float4 acc[12];
        #pragma unroll
        for (int q = 0; q < 12; ++q) acc[q] = ubuf[q];
        const float4* un = ub4 + (s + 1 < LCH ? (s + 1) * 12 : 15 * 12);
        #pragma unroll
        for (int q = 0; q < 12; ++q) ubuf[q] = un[q];
        #pragma unroll
        for (int j4 = 0; j4 < 12; ++j4) {
            const float4 mj = mo[j4];
            AMV_COL(0, mj.x)
            AMV_COL(1, mj.y)
            AMV_COL(2, mj.z)
            AMV_COL(3, mj.w)
        }
        #pragma unroll
        for (int q = 0; q < 12; ++q) mo[q] = acc[q];
    }

    float4* dst = reinterpret_cast<float4*>(out + S0_OFF + c * 48);
    #pragma unroll
    for (int q = 0; q < 12; ++q) dst[q] = mo[q];
}

// ---------------- phase 2: sequential boundary combine per batch (readlane) ----------------
__global__ __launch_bounds__(64) void k_p2(float* __restrict__ out)
{
    const int lane = threadIdx.x;
    const int b    = blockIdx.x;
    const int h    = lane < H_ ? lane : 0;

    const float* A16 = out + A16_OFF;
    float w16[48];
    #pragma unroll
    for (int j = 0; j < 48; ++j) w16[j] = A16[h * 48 + j];

    float E = 0.f;
    float s0 = out[S0_OFF + (((size_t)b << 7) | 0) * 48 + h];
    #pragma unroll 1
    for (int k = 0; k < KCH; ++k) {
        const size_t c = ((size_t)b << 7) | k;
        if (lane < H_) out[MIN_OFF + c * 48 + h] = E;   // state entering chunk k
        float a0 = s0, a1 = 0.f, a2 = 0.f, a3 = 0.f, a4 = 0.f, a5 = 0.f, a6 = 0.f, a7 = 0.f;
        if (k + 1 < KCH)                                 // prefetch next S0 (hidden under matvec)
            s0 = out[S0_OFF + (c + 1) * 48 + h];
        #pragma unroll
        for (int g = 0; g < 6; ++g) {
            const int j = 8 * g;
            const float m0 = __int_as_float(__builtin_amdgcn_readlane(__float_as_int(E), j + 0));
            const float m1 = __int_as_float(__builtin_amdgcn_readlane(__float_as_int(E), j + 1));
            const float m2 = __int_as_float(__builtin_amdgcn_readlane(__float_as_int(E), j + 2));
            const float m3 = __int_as_float(__builtin_amdgcn_readlane(__float_as_int(E), j + 3));
            const float m4 = __int_as_float(__builtin_amdgcn_readlane(__float_as_int(E), j + 4));
            const float m5 = __int_as_float(__builtin_amdgcn_readlane(__float_as_int(E), j + 5));
            const float m6 = __int_as_float(__builtin_amdgcn_readlane(__float_as_int(E), j + 6));
            const float m7 = __int_as_float(__builtin_amdgcn_readlane(__float_as_int(E), j + 7));
            a0 = fmaf(m0, w16[j + 0], a0);
            a1 = fmaf(m1, w16[j + 1], a1);
            a2 = fmaf(m2, w16[j + 2], a2);
            a3 = fmaf(m3, w16[j + 3], a3);
            a4 = fmaf(m4, w16[j + 4], a4);
            a5 = fmaf(m5, w16[j + 5], a5);
            a6 = fmaf(m6, w16[j + 6], a6);
            a7 = fmaf(m7, w16[j + 7], a7);
        }
        E = ((a0 + a1) + (a2 + a3)) + ((a4 + a5) + (a6 + a7));
    }
}

// ---------------- phase 3: re-run chunks from corrected starts; emit z + zsum partials ----------------
__global__ __launch_bounds__(256) void k_p3(
    const float* __restrict__ Wmem, float* __restrict__ out)
{
    __shared__ float sAT[48 * 48];
    const int tid = threadIdx.x;
    for (int idx = tid; idx < 2304; idx += 256) {
        const int i = idx / 48, j = idx - i * 48;
        sAT[j * 48 + i] = 0.1f * Wmem[idx] + (i == j ? 0.9f : 0.0f);
    }
    __syncthreads();

    const size_t c = (size_t)blockIdx.x * 256 + tid;
    const float4* ub4 = reinterpret_cast<const float4*>(out + c * 768);
    float4* zb4 = reinterpret_cast<float4*>(out + Z_OFF + c * 768);   // z std layout == c*768

    float4 mo[12], ubuf[12], zsum[12];
    {
        const float4* m4 = reinterpret_cast<const float4*>(out + MIN_OFF + c * 48);
        #pragma unroll
        for (int q = 0; q < 12; ++q) mo[q] = m4[q];
    }
    #pragma unroll
    for (int q = 0; q < 12; ++q) zsum[q] = make_float4(0.f, 0.f, 0.f, 0.f);
    #pragma unroll
    for (int q = 0; q < 12; ++q) ubuf[q] = ub4[q];

    const float kExp = -0.14426950408889634f;  // -0.1*log2(e): z = sigmoid(ms/10)

    #pragma unroll 1
    for (int s = 0; s < LCH; ++s) {
        float4 acc[12];
        #pragma unroll
        for (int q = 0; q < 12; ++q) acc[q] = ubuf[q];
        const float4* un = ub4 + (s + 1 < LCH ? (s + 1) * 12 : 15 * 12);
        #pragma unroll
        for (int q = 0; q < 12; ++q) ubuf[q] = un[q];
        #pragma unroll
        for (int j4 = 0; j4 < 12; ++j4) {
            const float4 mj = mo[j4];
            AMV_COL(0, mj.x)
            AMV_COL(1, mj.y)
            AMV_COL(2, mj.z)
            AMV_COL(3, mj.w)
        }
        // z = sigmoid(acc/10); store + accumulate
        float4* zd = zb4 + s * 12;
        #pragma unroll
        for (int q = 0; q < 12; ++q) {
            float4 zq;
            zq.x = __builtin_amdgcn_rcpf(1.0f + __builtin_amdgcn_exp2f(acc[q].x * kExp));
            zq.y = __builtin_amdgcn_rcpf(1.0f + __builtin_amdgcn_exp2f(acc[q].y * kExp));
            zq.z = __builtin_amdgcn_rcpf(1.0f + __builtin_amdgcn_exp2f(acc[q].z * kExp));
            zq.w = __builtin_amdgcn_rcpf(1.0f + __builtin_amdgcn_exp2f(acc[q].w * kExp));
            zsum[q].x += zq.x; zsum[q].y += zq.y; zsum[q].z += zq.z; zsum[q].w += zq.w;
            zd[q] = zq;
        }
        #pragma unroll
        for (int q = 0; q < 12; ++q) mo[q] = acc[q];
    }

    float4* zp = reinterpret_cast<float4*>(out + ZP_OFF + c * 48);
    #pragma unroll
    for (int q = 0; q < 12; ++q) zp[q] = zsum[q];
}

// ---------------- classifier: reduce zsum partials, logits ----------------
__global__ __launch_bounds__(64) void k_cls(
    const float* __restrict__ Wcls, const float* __restrict__ bcls,
    float* __restrict__ out)
{
    __shared__ float sz[48];
    const int lane = threadIdx.x;
    const int b    = blockIdx.x;
    if (lane < 48) {
        float acc = 0.f;
        #pragma unroll 4
        for (int k = 0; k < KCH; ++k)
            acc += out[ZP_OFF + (((size_t)b << 7) | k) * 48 + lane];
        sz[lane] = acc;
    }
    __syncthreads();
    if (lane < C_) {
        float acc = 0.f;
        #pragma unroll
        for (int h = 0; h < 48; ++h) acc = fmaf(sz[h], Wcls[lane * 48 + h], acc);
        out[RECON_FLOATS + (size_t)b * C_ + lane] = acc * (1.0f / (float)T_) + bcls[lane];
    }
}

// ---------------- decoder GEMM (round-8 verbatim) ----------------
__global__ __launch_bounds__(256) void k_dec(
    const float* __restrict__ Wdec, const float* __restrict__ bdec,
    float* __restrict__ out)
{
    __shared__ float sz[256][52];
    __shared__ float swT[48][68];
    __shared__ float sbd[64];

    const int tid = threadIdx.x;

    #pragma unroll
    for (int m = 0; m < 12; ++m) {
        const int idx = tid + 256 * m;
        const int d = idx / 48, hh = idx - d * 48;
        swT[hh][d] = Wdec[idx];
    }
    if (tid < 64) sbd[tid] = bdec[tid];

    {
        const float4* zf4 = reinterpret_cast<const float4*>(out + Z_OFF) + (size_t)blockIdx.x * 3072;
        #pragma unroll
        for (int m = 0; m < 12; ++m) {
            const int idx = tid + 256 * m;
            const int row = idx / 12, c4 = idx - row * 12;
            *reinterpret_cast<float4*>(&sz[row][c4 * 4]) = zf4[idx];
        }
    }
    __syncthreads();

    const int lane = tid & 63;
    const int wv   = tid >> 6;
    const int rg   = lane >> 3;
    const int cg   = lane & 7;
    const int rowb = wv * 64 + rg;
    const int colb = cg * 8;

    float acc[8][8];
    {
        float bd[8];
        *reinterpret_cast<float4*>(&bd[0]) = *reinterpret_cast<const float4*>(&sbd[colb]);
        *reinterpret_cast<float4*>(&bd[4]) = *reinterpret_cast<const float4*>(&sbd[colb + 4]);
        #pragma unroll
        for (int k = 0; k < 8; ++k)
            #pragma unroll
            for (int c = 0; c < 8; ++c) acc[k][c] = bd[c];
    }

    #pragma unroll 2
    for (int h4 = 0; h4 < 12; ++h4) {
        float4 zf[8];
        #pragma unroll
        for (int k = 0; k < 8; ++k)
            zf[k] = *reinterpret_cast<const float4*>(&sz[rowb + 8 * k][h4 * 4]);
        #pragma unroll
        for (int j = 0; j < 4; ++j) {
            const float4 w0 = *reinterpret_cast<const float4*>(&swT[h4 * 4 + j][colb]);
            const float4 w1 = *reinterpret_cast<const float4*>(&swT[h4 * 4 + j][colb + 4]);
            #pragma unroll
            for (int k = 0; k < 8; ++k) {
                const float zv = j == 0 ? zf[k].x : (j == 1 ? zf[k].y : (j == 2 ? zf[k].z : zf[k].w));
                acc[k][0] = fmaf(zv, w0.x, acc[k][0]);
                acc[k][1] = fmaf(zv, w0.y, acc[k][1]);
                acc[k][2] = fmaf(zv, w0.z, acc[k][2]);
                acc[k][3] = fmaf(zv, w0.w, acc[k][3]);
                acc[k][4] = fmaf(zv, w1.x, acc[k][4]);
                acc[k][5] = fmaf(zv, w1.y, acc[k][5]);
                acc[k][6] = fmaf(zv, w1.z, acc[k][6]);
                acc[k][7] = fmaf(zv, w1.w, acc[k][7]);
            }
        }
    }

    const size_t row0 = (size_t)blockIdx.x * 256 + rowb;
    #pragma unroll
    for (int k = 0; k < 8; ++k) {
        float* dst = out + (row0 + 8 * k) * 64 + colb;
        *reinterpret_cast<float4*>(dst)     = make_float4(acc[k][0], acc[k][1], acc[k][2], acc[k][3]);
        *reinterpret_cast<float4*>(dst + 4) = make_float4(acc[k][4], acc[k][5], acc[k][6], acc[k][7]);
    }
}

extern "C" void kernel_launch(void* const* d_in, const int* in_sizes, int n_in,
                              void* d_out, int out_size, void* d_ws, size_t ws_size,
                              hipStream_t stream) {
    const float* x    = (const float*)d_in[0];
    const float* Wenc = (const float*)d_in[1];
    const float* benc = (const float*)d_in[2];
    const float* Wmem = (const float*)d_in[3];
    const float* bmem = (const float*)d_in[4];
    const float* Wdec = (const float*)d_in[5];
    const float* bdec = (const float*)d_in[6];
    const float* Wcls = (const float*)d_in[7];
    const float* bcls = (const float*)d_in[8];
    float* out = (float*)d_out;

    k_powA<<<dim3(1), dim3(576), 0, stream>>>(Wmem, out);
    k_enc<<<dim3((B_ * T_) / 128), dim3(128), 0, stream>>>(x, Wenc, benc, bmem, out);
    k_p1<<<dim3(NC / 256), dim3(256), 0, stream>>>(Wmem, out);
    k_p2<<<dim3(B_), dim3(64), 0, stream>>>(out);
    k_p3<<<dim3(NC / 256), dim3(256), 0, stream>>>(Wmem, out);
    k_cls<<<dim3(B_), dim3(64), 0, stream>>>(Wcls, bcls, out);
    k_dec<<<dim3((B_ * T_) / 256), dim3(256), 0, stream>>>(Wdec, bdec, out);
}

// Round 11
// 626.630 us; speedup vs baseline: 7.5365x; 7.5365x over previous
//
#include <hip/hip_runtime.h>
#include <cstdint>
#include <cstddef>

#define B_ 512
#define T_ 2048
#define D_ 64
#define H_ 48
#define C_ 3
#define LCH 16           // chunk length
#define KCH 128          // chunks per batch
#define NC  65536        // total chains = B_*KCH

#define RECON_FLOATS ((size_t)B_ * T_ * D_)            // 67,108,864 floats (output 0)
#define LOGIT_FLOATS ((size_t)B_ * C_)                 // 1536 floats      (output 1)
#define Z_OFF        (RECON_FLOATS + LOGIT_FLOATS)     // z region         (output 2)
// scratch inside the recon region (dec overwrites it LAST):
// u (std layout [b][t][48]) at 0 .. 50,331,648
#define S0_OFF   ((size_t)50331648)                    // S0[c][48]   (ms-space chunk-end, zero-init)
#define MIN_OFF  ((size_t)53477376)                    // M_in[c][48] (ms-space chunk-entry state)
#define ZP_OFF   ((size_t)56623104)                    // zsum_part[c][48]
#define A16_OFF  ((size_t)59768832)                    // A^16 (2304 floats)

// ---------------- encoder GEMM (round-8 verbatim): u[r][48] = x row . Wenc^T + (benc+bmem) ----------------
__global__ __launch_bounds__(128) void k_enc(
    const float* __restrict__ x, const float* __restrict__ Wenc,
    const float* __restrict__ benc, const float* __restrict__ bmem,
    float* __restrict__ out)
{
    __shared__ float sx[128][68];
    __shared__ float sw[48][68];
    __shared__ float sbe[48];

    const int tid = threadIdx.x;

    {
        const float4* wf4 = reinterpret_cast<const float4*>(Wenc);
        #pragma unroll
        for (int m = 0; m < 6; ++m) {
            const int idx = tid + 128 * m;
            const int c = idx >> 4, d4 = idx & 15;
            *reinterpret_cast<float4*>(&sw[c][d4 * 4]) = wf4[idx];
        }
    }
    if (tid < 48) sbe[tid] = benc[tid] + bmem[tid];

    {
        const float4* xf4 = reinterpret_cast<const float4*>(x) + (size_t)blockIdx.x * 2048;
        #pragma unroll
        for (int m = 0; m < 16; ++m) {
            const int idx = tid + 128 * m;
            const int row = idx >> 4, d4 = idx & 15;
            *reinterpret_cast<float4*>(&sx[row][d4 * 4]) = xf4[idx];
        }
    }
    __syncthreads();

    const int lane = tid & 63;
    const int wv   = tid >> 6;
    const int rg   = lane >> 2;
    const int cg   = lane & 3;
    const int rowb = wv * 64 + rg;
    const int colb = cg * 12;

    float acc[4][12];
    {
        float bia[12];
        #pragma unroll
        for (int m = 0; m < 3; ++m)
            *reinterpret_cast<float4*>(&bia[4 * m]) = *reinterpret_cast<const float4*>(&sbe[colb + 4 * m]);
        #pragma unroll
        for (int k = 0; k < 4; ++k)
            #pragma unroll
            for (int i = 0; i < 12; ++i) acc[k][i] = bia[i];
    }

    #pragma unroll 2
    for (int d4 = 0; d4 < 16; ++d4) {
        float4 xf[4];
        #pragma unroll
        for (int k = 0; k < 4; ++k)
            xf[k] = *reinterpret_cast<const float4*>(&sx[rowb + 16 * k][d4 * 4]);
        #pragma unroll
        for (int i = 0; i < 12; ++i) {
            const float4 wvv = *reinterpret_cast<const float4*>(&sw[colb + i][d4 * 4]);
            #pragma unroll
            for (int k = 0; k < 4; ++k)
                acc[k][i] = fmaf(xf[k].x, wvv.x, fmaf(xf[k].y, wvv.y,
                             fmaf(xf[k].z, wvv.z, fmaf(xf[k].w, wvv.w, acc[k][i]))));
        }
    }

    const size_t row0 = (size_t)blockIdx.x * 128 + rowb;
    #pragma unroll
    for (int k = 0; k < 4; ++k) {
        float* dst = out + (row0 + 16 * k) * 48 + colb;
        #pragma unroll
        for (int m = 0; m < 3; ++m)
            *reinterpret_cast<float4*>(dst + 4 * m) =
                make_float4(acc[k][4 * m], acc[k][4 * m + 1], acc[k][4 * m + 2], acc[k][4 * m + 3]);
    }
}

// ---------------- A^16 via 4 squarings ----------------
__global__ __launch_bounds__(576) void k_powA(
    const float* __restrict__ Wmem, float* __restrict__ out)
{
    __shared__ float a0[48 * 49];
    __shared__ float a1[48 * 49];
    const int tid = threadIdx.x;

    for (int idx = tid; idx < 2304; idx += 576) {
        const int i = idx / 48, j = idx - i * 48;
        a0[i * 49 + j] = 0.1f * Wmem[idx] + (i == j ? 0.9f : 0.0f);
    }
    __syncthreads();

    float* src = a0;
    float* dst = a1;
    #pragma unroll 1
    for (int it = 0; it < 4; ++it) {
        float v[4];
        #pragma unroll
        for (int q = 0; q < 4; ++q) {
            const int o = tid + 576 * q;
            const int i = o / 48, j = o - i * 48;
            float acc = 0.f;
            #pragma unroll
            for (int k = 0; k < 48; ++k)
                acc = fmaf(src[i * 49 + k], src[k * 49 + j], acc);
            v[q] = acc;
        }
        #pragma unroll
        for (int q = 0; q < 4; ++q) {
            const int o = tid + 576 * q;
            const int i = o / 48, j = o - i * 48;
            dst[i * 49 + j] = v[q];
        }
        __syncthreads();
        float* t = src; src = dst; dst = t;
    }
    for (int idx = tid; idx < 2304; idx += 576) {
        const int i = idx / 48, j = idx - i * 48;
        out[A16_OFF + idx] = src[i * 49 + j];
    }
}

// one recurrence step in ms-space, k_rec-proven readlane form:
// E_new(lane h) = 0.9*E + u_h + sum_j 0.1*W[h][j]*readlane(E, j)
#define REC_STEP(E, UVAL)                                                                     \
    {                                                                                         \
        float a0 = fmaf(0.9f, (E), (UVAL));                                                   \
        float a1 = 0.f, a2 = 0.f, a3 = 0.f, a4 = 0.f, a5 = 0.f, a6 = 0.f, a7 = 0.f;           \
        _Pragma("unroll")                                                                     \
        for (int g = 0; g < 6; ++g) {                                                         \
            const int j = 8 * g;                                                              \
            const float m0 = __int_as_float(__builtin_amdgcn_readlane(__float_as_int(E), j + 0)); \
            const float m1 = __int_as_float(__builtin_amdgcn_readlane(__float_as_int(E), j + 1)); \
            const float m2 = __int_as_float(__builtin_amdgcn_readlane(__float_as_int(E), j + 2)); \
            const float m3 = __int_as_float(__builtin_amdgcn_readlane(__float_as_int(E), j + 3)); \
            const float m4 = __int_as_float(__builtin_amdgcn_readlane(__float_as_int(E), j + 4)); \
            const float m5 = __int_as_float(__builtin_amdgcn_readlane(__float_as_int(E), j + 5)); \
            const float m6 = __int_as_float(__builtin_amdgcn_readlane(__float_as_int(E), j + 6)); \
            const float m7 = __int_as_float(__builtin_amdgcn_readlane(__float_as_int(E), j + 7)); \
            a0 = fmaf(m0, wm[j + 0], a0);                                                     \
            a1 = fmaf(m1, wm[j + 1], a1);                                                     \
            a2 = fmaf(m2, wm[j + 2], a2);                                                     \
            a3 = fmaf(m3, wm[j + 3], a3);                                                     \
            a4 = fmaf(m4, wm[j + 4], a4);                                                     \
            a5 = fmaf(m5, wm[j + 5], a5);                                                     \
            a6 = fmaf(m6, wm[j + 6], a6);                                                     \
            a7 = fmaf(m7, wm[j + 7], a7);                                                     \
        }                                                                                     \
        (E) = ((a0 + a1) + (a2 + a3)) + ((a4 + a5) + (a6 + a7));                              \
    }

// ---------------- phase 1: chunk-end states from zero; ONE CHAIN PER WAVE ----------------
__global__ __launch_bounds__(256) void k_p1(
    const float* __restrict__ Wmem, float* __restrict__ out)
{
    __shared__ float su[4][LCH * 48];    // per-wave chunk staging (3 KB each)
    const int tid  = threadIdx.x;
    const int lane = tid & 63;
    const int wv   = tid >> 6;
    const int h    = lane < H_ ? lane : 0;
    const size_t c = (size_t)blockIdx.x * 4 + wv;

    float wm[48];
    #pragma unroll
    for (int j = 0; j < 48; ++j) wm[j] = 0.1f * Wmem[h * 48 + j];

    // stage this wave's u chunk (768 floats, coalesced)
    {
        const float4* ub4 = reinterpret_cast<const float4*>(out + c * 768);
        const float4 t0 = ub4[lane], t1 = ub4[64 + lane], t2 = ub4[128 + lane];
        float4* sdst = reinterpret_cast<float4*>(&su[wv][0]);
        sdst[lane] = t0; sdst[64 + lane] = t1; sdst[128 + lane] = t2;
    }
    __syncthreads();

    float E = 0.f;
    const float* sut = su[wv];
    #pragma unroll 1
    for (int s = 0; s < LCH; ++s) {
        const float uuv = sut[s * 48 + h];
        REC_STEP(E, uuv)
    }

    if (lane < H_) out[S0_OFF + c * 48 + h] = E;
}

// ---------------- phase 2: sequential boundary combine per batch (readlane w/ A^16) ----------------
__global__ __launch_bounds__(64) void k_p2(float* __restrict__ out)
{
    const int lane = threadIdx.x;
    const int b    = blockIdx.x;
    const int h    = lane < H_ ? lane : 0;

    const float* A16 = out + A16_OFF;
    float w16[48];
    #pragma unroll
    for (int j = 0; j < 48; ++j) w16[j] = A16[h * 48 + j];

    float E = 0.f;
    float s0 = out[S0_OFF + (((size_t)b << 7) | 0) * 48 + h];
    #pragma unroll 1
    for (int k = 0; k < KCH; ++k) {
        const size_t c = ((size_t)b << 7) | k;
        if (lane < H_) out[MIN_OFF + c * 48 + h] = E;
        float a0 = s0, a1 = 0.f, a2 = 0.f, a3 = 0.f, a4 = 0.f, a5 = 0.f, a6 = 0.f, a7 = 0.f;
        if (k + 1 < KCH) s0 = out[S0_OFF + (c + 1) * 48 + h];
        #pragma unroll
        for (int g = 0; g < 6; ++g) {
            const int j = 8 * g;
            const float m0 = __int_as_float(__builtin_amdgcn_readlane(__float_as_int(E), j + 0));
            const float m1 = __int_as_float(__builtin_amdgcn_readlane(__float_as_int(E), j + 1));
            const float m2 = __int_as_float(__builtin_amdgcn_readlane(__float_as_int(E), j + 2));
            const float m3 = __int_as_float(__builtin_amdgcn_readlane(__float_as_int(E), j + 3));
            const float m4 = __int_as_float(__builtin_amdgcn_readlane(__float_as_int(E), j + 4));
            const float m5 = __int_as_float(__builtin_amdgcn_readlane(__float_as_int(E), j + 5));
            const float m6 = __int_as_float(__builtin_amdgcn_readlane(__float_as_int(E), j + 6));
            const float m7 = __int_as_float(__builtin_amdgcn_readlane(__float_as_int(E), j + 7));
            a0 = fmaf(m0, w16[j + 0], a0);
            a1 = fmaf(m1, w16[j + 1], a1);
            a2 = fmaf(m2, w16[j + 2], a2);
            a3 = fmaf(m3, w16[j + 3], a3);
            a4 = fmaf(m4, w16[j + 4], a4);
            a5 = fmaf(m5, w16[j + 5], a5);
            a6 = fmaf(m6, w16[j + 6], a6);
            a7 = fmaf(m7, w16[j + 7], a7);
        }
        E = ((a0 + a1) + (a2 + a3)) + ((a4 + a5) + (a6 + a7));
    }
}

// ---------------- phase 3: re-run chunks from corrected starts; ONE CHAIN PER WAVE ----------------
__global__ __launch_bounds__(256) void k_p3(
    const float* __restrict__ Wmem, float* __restrict__ out)
{
    __shared__ float su[4][LCH * 48];
    const int tid  = threadIdx.x;
    const int lane = tid & 63;
    const int wv   = tid >> 6;
    const int h    = lane < H_ ? lane : 0;
    const size_t c = (size_t)blockIdx.x * 4 + wv;

    float wm[48];
    #pragma unroll
    for (int j = 0; j < 48; ++j) wm[j] = 0.1f * Wmem[h * 48 + j];

    {
        const float4* ub4 = reinterpret_cast<const float4*>(out + c * 768);
        const float4 t0 = ub4[lane], t1 = ub4[64 + lane], t2 = ub4[128 + lane];
        float4* sdst = reinterpret_cast<float4*>(&su[wv][0]);
        sdst[lane] = t0; sdst[64 + lane] = t1; sdst[128 + lane] = t2;
    }

    float E = out[MIN_OFF + c * 48 + h];   // corrected chunk-entry state (ms-space)
    __syncthreads();

    float* zb = out + Z_OFF + c * 768;
    const float* sut = su[wv];
    const float kExp = -0.14426950408889634f;  // -0.1*log2(e): z = sigmoid(E/10)
    float zs = 0.f;

    #pragma unroll 1
    for (int s = 0; s < LCH; ++s) {
        const float uuv = sut[s * 48 + h];
        REC_STEP(E, uuv)
        const float e2 = __builtin_amdgcn_exp2f(E * kExp);
        const float z  = __builtin_amdgcn_rcpf(1.0f + e2);
        if (lane < H_) {
            zb[s * 48 + lane] = z;
            zs += z;
        }
    }

    if (lane < H_) out[ZP_OFF + c * 48 + h] = zs;
}

// ---------------- classifier: reduce zsum partials, logits ----------------
__global__ __launch_bounds__(64) void k_cls(
    const float* __restrict__ Wcls, const float* __restrict__ bcls,
    float* __restrict__ out)
{
    __shared__ float sz[48];
    const int lane = threadIdx.x;
    const int b    = blockIdx.x;
    if (lane < 48) {
        float acc = 0.f;
        #pragma unroll 4
        for (int k = 0; k < KCH; ++k)
            acc += out[ZP_OFF + (((size_t)b << 7) | k) * 48 + lane];
        sz[lane] = acc;
    }
    __syncthreads();
    if (lane < C_) {
        float acc = 0.f;
        #pragma unroll
        for (int h = 0; h < 48; ++h) acc = fmaf(sz[h], Wcls[lane * 48 + h], acc);
        out[RECON_FLOATS + (size_t)b * C_ + lane] = acc * (1.0f / (float)T_) + bcls[lane];
    }
}

// ---------------- decoder GEMM (round-8 verbatim) ----------------
__global__ __launch_bounds__(256) void k_dec(
    const float* __restrict__ Wdec, const float* __restrict__ bdec,
    float* __restrict__ out)
{
    __shared__ float sz[256][52];
    __shared__ float swT[48][68];
    __shared__ float sbd[64];

    const int tid = threadIdx.x;

    #pragma unroll
    for (int m = 0; m < 12; ++m) {
        const int idx = tid + 256 * m;
        const int d = idx / 48, hh = idx - d * 48;
        swT[hh][d] = Wdec[idx];
    }
    if (tid < 64) sbd[tid] = bdec[tid];

    {
        const float4* zf4 = reinterpret_cast<const float4*>(out + Z_OFF) + (size_t)blockIdx.x * 3072;
        #pragma unroll
        for (int m = 0; m < 12; ++m) {
            const int idx = tid + 256 * m;
            const int row = idx / 12, c4 = idx - row * 12;
            *reinterpret_cast<float4*>(&sz[row][c4 * 4]) = zf4[idx];
        }
    }
    __syncthreads();

    const int lane = tid & 63;
    const int wv   = tid >> 6;
    const int rg   = lane >> 3;
    const int cg   = lane & 7;
    const int rowb = wv * 64 + rg;
    const int colb = cg * 8;

    float acc[8][8];
    {
        float bd[8];
        *reinterpret_cast<float4*>(&bd[0]) = *reinterpret_cast<const float4*>(&sbd[colb]);
        *reinterpret_cast<float4*>(&bd[4]) = *reinterpret_cast<const float4*>(&sbd[colb + 4]);
        #pragma unroll
        for (int k = 0; k < 8; ++k)
            #pragma unroll
            for (int c = 0; c < 8; ++c) acc[k][c] = bd[c];
    }

    #pragma unroll 2
    for (int h4 = 0; h4 < 12; ++h4) {
        float4 zf[8];
        #pragma unroll
        for (int k = 0; k < 8; ++k)
            zf[k] = *reinterpret_cast<const float4*>(&sz[rowb + 8 * k][h4 * 4]);
        #pragma unroll
        for (int j = 0; j < 4; ++j) {
            const float4 w0 = *reinterpret_cast<const float4*>(&swT[h4 * 4 + j][colb]);
            const float4 w1 = *reinterpret_cast<const float4*>(&swT[h4 * 4 + j][colb + 4]);
            #pragma unroll
            for (int k = 0; k < 8; ++k) {
                const float zv = j == 0 ? zf[k].x : (j == 1 ? zf[k].y : (j == 2 ? zf[k].z : zf[k].w));
                acc[k][0] = fmaf(zv, w0.x, acc[k][0]);
                acc[k][1] = fmaf(zv, w0.y, acc[k][1]);
                acc[k][2] = fmaf(zv, w0.z, acc[k][2]);
                acc[k][3] = fmaf(zv, w0.w, acc[k][3]);
                acc[k][4] = fmaf(zv, w1.x, acc[k][4]);
                acc[k][5] = fmaf(zv, w1.y, acc[k][5]);
                acc[k][6] = fmaf(zv, w1.z, acc[k][6]);
                acc[k][7] = fmaf(zv, w1.w, acc[k][7]);
            }
        }
    }

    const size_t row0 = (size_t)blockIdx.x * 256 + rowb;
    #pragma unroll
    for (int k = 0; k < 8; ++k) {
        float* dst = out + (row0 + 8 * k) * 64 + colb;
        *reinterpret_cast<float4*>(dst)     = make_float4(acc[k][0], acc[k][1], acc[k][2], acc[k][3]);
        *reinterpret_cast<float4*>(dst + 4) = make_float4(acc[k][4], acc[k][5], acc[k][6], acc[k][7]);
    }
}

extern "C" void kernel_launch(void* const* d_in, const int* in_sizes, int n_in,
                              void* d_out, int out_size, void* d_ws, size_t ws_size,
                              hipStream_t stream) {
    const float* x    = (const float*)d_in[0];
    const float* Wenc = (const float*)d_in[1];
    const float* benc = (const float*)d_in[2];
    const float* Wmem = (const float*)d_in[3];
    const float* bmem = (const float*)d_in[4];
    const float* Wdec = (const float*)d_in[5];
    const float* bdec = (const float*)d_in[6];
    const float* Wcls = (const float*)d_in[7];
    const float* bcls = (const float*)d_in[8];
    float* out = (float*)d_out;

    k_powA<<<dim3(1), dim3(576), 0, stream>>>(Wmem, out);
    k_enc<<<dim3((B_ * T_) / 128), dim3(128), 0, stream>>>(x, Wenc, benc, bmem, out);
    k_p1<<<dim3(NC / 4), dim3(256), 0, stream>>>(Wmem, out);
    k_p2<<<dim3(B_), dim3(64), 0, stream>>>(out);
    k_p3<<<dim3(NC / 4), dim3(256), 0, stream>>>(Wmem, out);
    k_cls<<<dim3(B_), dim3(64), 0, stream>>>(Wcls, bcls, out);
    k_dec<<<dim3((B_ * T_) / 256), dim3(256), 0, stream>>>(Wdec, bdec, out);
}

// Round 12
// 609.751 us; speedup vs baseline: 7.7451x; 1.0277x over previous
//
#include <hip/hip_runtime.h>
#include <cstdint>
#include <cstddef>

#define B_ 512
#define T_ 2048
#define D_ 64
#define H_ 48
#define C_ 3
#define LCH 16           // chunk length
#define KCH 128          // chunks per batch
#define NC  65536        // total chains = B_*KCH

#define RECON_FLOATS ((size_t)B_ * T_ * D_)            // 67,108,864 floats (output 0)
#define LOGIT_FLOATS ((size_t)B_ * C_)                 // 1536 floats      (output 1)
#define Z_OFF        (RECON_FLOATS + LOGIT_FLOATS)     // z region         (output 2)
// scratch inside the recon region (dec overwrites it LAST):
// u (std layout [b][t][48]) at 0 .. 50,331,648
#define S0_OFF   ((size_t)50331648)                    // S0[c][48]   (ms-space chunk-end, zero-init)
#define MIN_OFF  ((size_t)53477376)                    // M_in[c][48] (ms-space chunk-entry state)
#define ZP_OFF   ((size_t)56623104)                    // zsum_part[c][48]
#define A16_OFF  ((size_t)59768832)                    // A^16 (2304 floats)

// ---------------- encoder GEMM (round-8 verbatim) ----------------
__global__ __launch_bounds__(128) void k_enc(
    const float* __restrict__ x, const float* __restrict__ Wenc,
    const float* __restrict__ benc, const float* __restrict__ bmem,
    float* __restrict__ out)
{
    __shared__ float sx[128][68];
    __shared__ float sw[48][68];
    __shared__ float sbe[48];

    const int tid = threadIdx.x;

    {
        const float4* wf4 = reinterpret_cast<const float4*>(Wenc);
        #pragma unroll
        for (int m = 0; m < 6; ++m) {
            const int idx = tid + 128 * m;
            const int c = idx >> 4, d4 = idx & 15;
            *reinterpret_cast<float4*>(&sw[c][d4 * 4]) = wf4[idx];
        }
    }
    if (tid < 48) sbe[tid] = benc[tid] + bmem[tid];

    {
        const float4* xf4 = reinterpret_cast<const float4*>(x) + (size_t)blockIdx.x * 2048;
        #pragma unroll
        for (int m = 0; m < 16; ++m) {
            const int idx = tid + 128 * m;
            const int row = idx >> 4, d4 = idx & 15;
            *reinterpret_cast<float4*>(&sx[row][d4 * 4]) = xf4[idx];
        }
    }
    __syncthreads();

    const int lane = tid & 63;
    const int wv   = tid >> 6;
    const int rg   = lane >> 2;
    const int cg   = lane & 3;
    const int rowb = wv * 64 + rg;
    const int colb = cg * 12;

    float acc[4][12];
    {
        float bia[12];
        #pragma unroll
        for (int m = 0; m < 3; ++m)
            *reinterpret_cast<float4*>(&bia[4 * m]) = *reinterpret_cast<const float4*>(&sbe[colb + 4 * m]);
        #pragma unroll
        for (int k = 0; k < 4; ++k)
            #pragma unroll
            for (int i = 0; i < 12; ++i) acc[k][i] = bia[i];
    }

    #pragma unroll 2
    for (int d4 = 0; d4 < 16; ++d4) {
        float4 xf[4];
        #pragma unroll
        for (int k = 0; k < 4; ++k)
            xf[k] = *reinterpret_cast<const float4*>(&sx[rowb + 16 * k][d4 * 4]);
        #pragma unroll
        for (int i = 0; i < 12; ++i) {
            const float4 wvv = *reinterpret_cast<const float4*>(&sw[colb + i][d4 * 4]);
            #pragma unroll
            for (int k = 0; k < 4; ++k)
                acc[k][i] = fmaf(xf[k].x, wvv.x, fmaf(xf[k].y, wvv.y,
                             fmaf(xf[k].z, wvv.z, fmaf(xf[k].w, wvv.w, acc[k][i]))));
        }
    }

    const size_t row0 = (size_t)blockIdx.x * 128 + rowb;
    #pragma unroll
    for (int k = 0; k < 4; ++k) {
        float* dst = out + (row0 + 16 * k) * 48 + colb;
        #pragma unroll
        for (int m = 0; m < 3; ++m)
            *reinterpret_cast<float4*>(dst + 4 * m) =
                make_float4(acc[k][4 * m], acc[k][4 * m + 1], acc[k][4 * m + 2], acc[k][4 * m + 3]);
    }
}

// ---------------- A^16 via 4 squarings ----------------
__global__ __launch_bounds__(576) void k_powA(
    const float* __restrict__ Wmem, float* __restrict__ out)
{
    __shared__ float a0[48 * 49];
    __shared__ float a1[48 * 49];
    const int tid = threadIdx.x;

    for (int idx = tid; idx < 2304; idx += 576) {
        const int i = idx / 48, j = idx - i * 48;
        a0[i * 49 + j] = 0.1f * Wmem[idx] + (i == j ? 0.9f : 0.0f);
    }
    __syncthreads();

    float* src = a0;
    float* dst = a1;
    #pragma unroll 1
    for (int it = 0; it < 4; ++it) {
        float v[4];
        #pragma unroll
        for (int q = 0; q < 4; ++q) {
            const int o = tid + 576 * q;
            const int i = o / 48, j = o - i * 48;
            float acc = 0.f;
            #pragma unroll
            for (int k = 0; k < 48; ++k)
                acc = fmaf(src[i * 49 + k], src[k * 49 + j], acc);
            v[q] = acc;
        }
        #pragma unroll
        for (int q = 0; q < 4; ++q) {
            const int o = tid + 576 * q;
            const int i = o / 48, j = o - i * 48;
            dst[i * 49 + j] = v[q];
        }
        __syncthreads();
        float* t = src; src = dst; dst = t;
    }
    for (int idx = tid; idx < 2304; idx += 576) {
        const int i = idx / 48, j = idx - i * 48;
        out[A16_OFF + idx] = src[i * 49 + j];
    }
}

// static component select (j must be a compile-time-unrolled index)
#define MO_COMP(j) ((j & 3) == 0 ? mo[(j) >> 2].x : (j & 3) == 1 ? mo[(j) >> 2].y \
                   : (j & 3) == 2 ? mo[(j) >> 2].z : mo[(j) >> 2].w)

// ---------------- phase 1: chunk-end states from zero; ONE CHAIN PER LANE ----------------
__global__ __launch_bounds__(64, 2) void k_p1(
    const float* __restrict__ Wmem, float* __restrict__ out)
{
    __shared__ float sA[48 * 48];       // col-major: sA[j*48+i] = A[i][j]
    const int lane = threadIdx.x;
    for (int idx = lane; idx < 2304; idx += 64) {
        const int i = idx / 48, j = idx - i * 48;
        sA[j * 48 + i] = 0.1f * Wmem[idx] + (i == j ? 0.9f : 0.0f);
    }
    __syncthreads();

    const size_t c = (size_t)blockIdx.x * 64 + lane;
    const float4* ub4 = reinterpret_cast<const float4*>(out + c * 768);  // chain's u: 16 steps x 12 f4

    float4 mo[12];
    #pragma unroll
    for (int q = 0; q < 12; ++q) mo[q] = make_float4(0.f, 0.f, 0.f, 0.f);

    #pragma unroll 1
    for (int s = 0; s < LCH; ++s) {
        asm volatile("" ::: "memory");   // fence: keep A-column ds_reads & u loads inside the step
        float4 uu[12];
        #pragma unroll
        for (int q = 0; q < 12; ++q) uu[q] = ub4[s * 12 + q];   // issued early, used at step end
        float4 acc[12];
        #pragma unroll
        for (int q = 0; q < 12; ++q) acc[q] = make_float4(0.f, 0.f, 0.f, 0.f);
        #pragma unroll
        for (int j = 0; j < 48; ++j) {
            const float mj = MO_COMP(j);
            const float4* colp = reinterpret_cast<const float4*>(sA + j * 48);  // uniform -> broadcast
            #pragma unroll
            for (int q = 0; q < 12; ++q) {
                const float4 a = colp[q];
                acc[q].x = fmaf(a.x, mj, acc[q].x);
                acc[q].y = fmaf(a.y, mj, acc[q].y);
                acc[q].z = fmaf(a.z, mj, acc[q].z);
                acc[q].w = fmaf(a.w, mj, acc[q].w);
            }
        }
        #pragma unroll
        for (int q = 0; q < 12; ++q) {
            mo[q].x = acc[q].x + uu[q].x;
            mo[q].y = acc[q].y + uu[q].y;
            mo[q].z = acc[q].z + uu[q].z;
            mo[q].w = acc[q].w + uu[q].w;
        }
    }

    float4* dst = reinterpret_cast<float4*>(out + S0_OFF + c * 48);
    #pragma unroll
    for (int q = 0; q < 12; ++q) dst[q] = mo[q];
}

// ---------------- phase 2: sequential boundary combine per batch (r11 verbatim) ----------------
__global__ __launch_bounds__(64) void k_p2(float* __restrict__ out)
{
    const int lane = threadIdx.x;
    const int b    = blockIdx.x;
    const int h    = lane < H_ ? lane : 0;

    const float* A16 = out + A16_OFF;
    float w16[48];
    #pragma unroll
    for (int j = 0; j < 48; ++j) w16[j] = A16[h * 48 + j];

    float E = 0.f;
    float s0 = out[S0_OFF + (((size_t)b << 7) | 0) * 48 + h];
    #pragma unroll 1
    for (int k = 0; k < KCH; ++k) {
        const size_t c = ((size_t)b << 7) | k;
        if (lane < H_) out[MIN_OFF + c * 48 + h] = E;
        float a0 = s0, a1 = 0.f, a2 = 0.f, a3 = 0.f, a4 = 0.f, a5 = 0.f, a6 = 0.f, a7 = 0.f;
        if (k + 1 < KCH) s0 = out[S0_OFF + (c + 1) * 48 + h];
        #pragma unroll
        for (int g = 0; g < 6; ++g) {
            const int j = 8 * g;
            const float m0 = __int_as_float(__builtin_amdgcn_readlane(__float_as_int(E), j + 0));
            const float m1 = __int_as_float(__builtin_amdgcn_readlane(__float_as_int(E), j + 1));
            const float m2 = __int_as_float(__builtin_amdgcn_readlane(__float_as_int(E), j + 2));
            const float m3 = __int_as_float(__builtin_amdgcn_readlane(__float_as_int(E), j + 3));
            const float m4 = __int_as_float(__builtin_amdgcn_readlane(__float_as_int(E), j + 4));
            const float m5 = __int_as_float(__builtin_amdgcn_readlane(__float_as_int(E), j + 5));
            const float m6 = __int_as_float(__builtin_amdgcn_readlane(__float_as_int(E), j + 6));
            const float m7 = __int_as_float(__builtin_amdgcn_readlane(__float_as_int(E), j + 7));
            a0 = fmaf(m0, w16[j + 0], a0);
            a1 = fmaf(m1, w16[j + 1], a1);
            a2 = fmaf(m2, w16[j + 2], a2);
            a3 = fmaf(m3, w16[j + 3], a3);
            a4 = fmaf(m4, w16[j + 4], a4);
            a5 = fmaf(m5, w16[j + 5], a5);
            a6 = fmaf(m6, w16[j + 6], a6);
            a7 = fmaf(m7, w16[j + 7], a7);
        }
        E = ((a0 + a1) + (a2 + a3)) + ((a4 + a5) + (a6 + a7));
    }
}

// ---------------- phase 3: re-run chunks from corrected starts; ONE CHAIN PER LANE ----------------
__global__ __launch_bounds__(64, 2) void k_p3(
    const float* __restrict__ Wmem, float* __restrict__ out)
{
    __shared__ float sA[48 * 48];
    const int lane = threadIdx.x;
    for (int idx = lane; idx < 2304; idx += 64) {
        const int i = idx / 48, j = idx - i * 48;
        sA[j * 48 + i] = 0.1f * Wmem[idx] + (i == j ? 0.9f : 0.0f);
    }
    __syncthreads();

    const size_t c = (size_t)blockIdx.x * 64 + lane;
    const float4* ub4 = reinterpret_cast<const float4*>(out + c * 768);
    float4*       zb4 = reinterpret_cast<float4*>(out + Z_OFF + c * 768);

    float4 mo[12], zsum[12];
    {
        const float4* m4 = reinterpret_cast<const float4*>(out + MIN_OFF + c * 48);
        #pragma unroll
        for (int q = 0; q < 12; ++q) mo[q] = m4[q];
    }
    #pragma unroll
    for (int q = 0; q < 12; ++q) zsum[q] = make_float4(0.f, 0.f, 0.f, 0.f);

    const float kExp = -0.14426950408889634f;   // -0.1*log2(e): z = sigmoid(ms/10)

    #pragma unroll 1
    for (int s = 0; s < LCH; ++s) {
        asm volatile("" ::: "memory");
        float4 uu[12];
        #pragma unroll
        for (int q = 0; q < 12; ++q) uu[q] = ub4[s * 12 + q];
        float4 acc[12];
        #pragma unroll
        for (int q = 0; q < 12; ++q) acc[q] = make_float4(0.f, 0.f, 0.f, 0.f);
        #pragma unroll
        for (int j = 0; j < 48; ++j) {
            const float mj = MO_COMP(j);
            const float4* colp = reinterpret_cast<const float4*>(sA + j * 48);
            #pragma unroll
            for (int q = 0; q < 12; ++q) {
                const float4 a = colp[q];
                acc[q].x = fmaf(a.x, mj, acc[q].x);
                acc[q].y = fmaf(a.y, mj, acc[q].y);
                acc[q].z = fmaf(a.z, mj, acc[q].z);
                acc[q].w = fmaf(a.w, mj, acc[q].w);
            }
        }
        #pragma unroll
        for (int q = 0; q < 12; ++q) {
            mo[q].x = acc[q].x + uu[q].x;
            mo[q].y = acc[q].y + uu[q].y;
            mo[q].z = acc[q].z + uu[q].z;
            mo[q].w = acc[q].w + uu[q].w;
        }
        // z = sigmoid(mo/10): store + accumulate
        #pragma unroll
        for (int q = 0; q < 12; ++q) {
            float4 zq;
            zq.x = __builtin_amdgcn_rcpf(1.0f + __builtin_amdgcn_exp2f(mo[q].x * kExp));
            zq.y = __builtin_amdgcn_rcpf(1.0f + __builtin_amdgcn_exp2f(mo[q].y * kExp));
            zq.z = __builtin_amdgcn_rcpf(1.0f + __builtin_amdgcn_exp2f(mo[q].z * kExp));
            zq.w = __builtin_amdgcn_rcpf(1.0f + __builtin_amdgcn_exp2f(mo[q].w * kExp));
            zsum[q].x += zq.x; zsum[q].y += zq.y; zsum[q].z += zq.z; zsum[q].w += zq.w;
            zb4[s * 12 + q] = zq;
        }
    }

    float4* zp = reinterpret_cast<float4*>(out + ZP_OFF + c * 48);
    #pragma unroll
    for (int q = 0; q < 12; ++q) zp[q] = zsum[q];
}

// ---------------- classifier: reduce zsum partials, logits ----------------
__global__ __launch_bounds__(64) void k_cls(
    const float* __restrict__ Wcls, const float* __restrict__ bcls,
    float* __restrict__ out)
{
    __shared__ float sz[48];
    const int lane = threadIdx.x;
    const int b    = blockIdx.x;
    if (lane < 48) {
        float acc = 0.f;
        #pragma unroll 4
        for (int k = 0; k < KCH; ++k)
            acc += out[ZP_OFF + (((size_t)b << 7) | k) * 48 + lane];
        sz[lane] = acc;
    }
    __syncthreads();
    if (lane < C_) {
        float acc = 0.f;
        #pragma unroll
        for (int h = 0; h < 48; ++h) acc = fmaf(sz[h], Wcls[lane * 48 + h], acc);
        out[RECON_FLOATS + (size_t)b * C_ + lane] = acc * (1.0f / (float)T_) + bcls[lane];
    }
}

// ---------------- decoder GEMM (round-8 verbatim) ----------------
__global__ __launch_bounds__(256) void k_dec(
    const float* __restrict__ Wdec, const float* __restrict__ bdec,
    float* __restrict__ out)
{
    __shared__ float sz[256][52];
    __shared__ float swT[48][68];
    __shared__ float sbd[64];

    const int tid = threadIdx.x;

    #pragma unroll
    for (int m = 0; m < 12; ++m) {
        const int idx = tid + 256 * m;
        const int d = idx / 48, hh = idx - d * 48;
        swT[hh][d] = Wdec[idx];
    }
    if (tid < 64) sbd[tid] = bdec[tid];

    {
        const float4* zf4 = reinterpret_cast<const float4*>(out + Z_OFF) + (size_t)blockIdx.x * 3072;
        #pragma unroll
        for (int m = 0; m < 12; ++m) {
            const int idx = tid + 256 * m;
            const int row = idx / 12, c4 = idx - row * 12;
            *reinterpret_cast<float4*>(&sz[row][c4 * 4]) = zf4[idx];
        }
    }
    __syncthreads();

    const int lane = tid & 63;
    const int wv   = tid >> 6;
    const int rg   = lane >> 3;
    const int cg   = lane & 7;
    const int rowb = wv * 64 + rg;
    const int colb = cg * 8;

    float acc[8][8];
    {
        float bd[8];
        *reinterpret_cast<float4*>(&bd[0]) = *reinterpret_cast<const float4*>(&sbd[colb]);
        *reinterpret_cast<float4*>(&bd[4]) = *reinterpret_cast<const float4*>(&sbd[colb + 4]);
        #pragma unroll
        for (int k = 0; k < 8; ++k)
            #pragma unroll
            for (int c = 0; c < 8; ++c) acc[k][c] = bd[c];
    }

    #pragma unroll 2
    for (int h4 = 0; h4 < 12; ++h4) {
        float4 zf[8];
        #pragma unroll
        for (int k = 0; k < 8; ++k)
            zf[k] = *reinterpret_cast<const float4*>(&sz[rowb + 8 * k][h4 * 4]);
        #pragma unroll
        for (int j = 0; j < 4; ++j) {
            const float4 w0 = *reinterpret_cast<const float4*>(&swT[h4 * 4 + j][colb]);
            const float4 w1 = *reinterpret_cast<const float4*>(&swT[h4 * 4 + j][colb + 4]);
            #pragma unroll
            for (int k = 0; k < 8; ++k) {
                const float zv = j == 0 ? zf[k].x : (j == 1 ? zf[k].y : (j == 2 ? zf[k].z : zf[k].w));
                acc[k][0] = fmaf(zv, w0.x, acc[k][0]);
                acc[k][1] = fmaf(zv, w0.y, acc[k][1]);
                acc[k][2] = fmaf(zv, w0.z, acc[k][2]);
                acc[k][3] = fmaf(zv, w0.w, acc[k][3]);
                acc[k][4] = fmaf(zv, w1.x, acc[k][4]);
                acc[k][5] = fmaf(zv, w1.y, acc[k][5]);
                acc[k][6] = fmaf(zv, w1.z, acc[k][6]);
                acc[k][7] = fmaf(zv, w1.w, acc[k][7]);
            }
        }
    }

    const size_t row0 = (size_t)blockIdx.x * 256 + rowb;
    #pragma unroll
    for (int k = 0; k < 8; ++k) {
        float* dst = out + (row0 + 8 * k) * 64 + colb;
        *reinterpret_cast<float4*>(dst)     = make_float4(acc[k][0], acc[k][1], acc[k][2], acc[k][3]);
        *reinterpret_cast<float4*>(dst + 4) = make_float4(acc[k][4], acc[k][5], acc[k][6], acc[k][7]);
    }
}

extern "C" void kernel_launch(void* const* d_in, const int* in_sizes, int n_in,
                              void* d_out, int out_size, void* d_ws, size_t ws_size,
                              hipStream_t stream) {
    const float* x    = (const float*)d_in[0];
    const float* Wenc = (const float*)d_in[1];
    const float* benc = (const float*)d_in[2];
    const float* Wmem = (const float*)d_in[3];
    const float* bmem = (const float*)d_in[4];
    const float* Wdec = (const float*)d_in[5];
    const float* bdec = (const float*)d_in[6];
    const float* Wcls = (const float*)d_in[7];
    const float* bcls = (const float*)d_in[8];
    float* out = (float*)d_out;

    k_powA<<<dim3(1), dim3(576), 0, stream>>>(Wmem, out);
    k_enc<<<dim3((B_ * T_) / 128), dim3(128), 0, stream>>>(x, Wenc, benc, bmem, out);
    k_p1<<<dim3(NC / 64), dim3(64), 0, stream>>>(Wmem, out);
    k_p2<<<dim3(B_), dim3(64), 0, stream>>>(out);
    k_p3<<<dim3(NC / 64), dim3(64), 0, stream>>>(Wmem, out);
    k_cls<<<dim3(B_), dim3(64), 0, stream>>>(Wcls, bcls, out);
    k_dec<<<dim3((B_ * T_) / 256), dim3(256), 0, stream>>>(Wdec, bdec, out);
}